// Round 1
// baseline (378.786 us; speedup 1.0000x reference)
//
#include <hip/hip_runtime.h>

#define MMAX 2048

// ---------------- Kernel A: KNN (top-3 of 2048) + IDW interp + Linear1 ----------------
// One thread per vertex. Centroids staged in LDS as float4 (broadcast reads).
// W1/b1 read through wave-uniform indices -> scalar loads.
__global__ __launch_bounds__(128) void fp_knn_interp_mlp1(
    const float* __restrict__ verts,
    const float* __restrict__ cents,
    const float* __restrict__ feats,
    const float* __restrict__ W1,
    const float* __restrict__ b1,
    float* __restrict__ hout,
    int N, int M)
{
    __shared__ float4 cxyz[MMAX];
    for (int i = threadIdx.x; i < M; i += 128) {
        cxyz[i] = make_float4(cents[3*i+0], cents[3*i+1], cents[3*i+2], 0.0f);
    }
    __syncthreads();
    int tid = blockIdx.x * 128 + threadIdx.x;
    if (tid >= N) return;

    float vx = verts[3*tid+0], vy = verts[3*tid+1], vz = verts[3*tid+2];

    // top-3 smallest d^2, stable (earlier index wins ties) to match lax.top_k
    float c0 = 3.4e38f, c1 = 3.4e38f, c2 = 3.4e38f;
    int   i0 = 0, i1 = 0, i2 = 0;
    #pragma unroll 4
    for (int m = 0; m < M; ++m) {
        float4 c = cxyz[m];
        float dx = vx - c.x, dy = vy - c.y, dz = vz - c.z;
        float d2 = fmaf(dx, dx, fmaf(dy, dy, dz*dz));
        bool l0 = d2 < c0, l1 = d2 < c1, l2 = d2 < c2;
        c2 = l1 ? c1 : (l2 ? d2 : c2);
        i2 = l1 ? i1 : (l2 ? m  : i2);
        c1 = l0 ? c0 : (l1 ? d2 : c1);
        i1 = l0 ? i0 : (l1 ? m  : i1);
        c0 = l0 ? d2 : c0;
        i0 = l0 ? m  : i0;
    }

    // IDW weights, P=2: w = 1/d^2 = 1/d2 (no sqrt). Zero-distance path per reference.
    bool z0 = (c0 == 0.0f), z1 = (c1 == 0.0f), z2 = (c2 == 0.0f);
    float w0, w1, w2;
    if (z0 || z1 || z2) {
        w0 = z0 ? 1.0f : 0.0f;
        w1 = z1 ? 1.0f : 0.0f;
        w2 = z2 ? 1.0f : 0.0f;
    } else {
        w0 = 1.0f / c0; w1 = 1.0f / c1; w2 = 1.0f / c2;
    }
    float winv = 1.0f / (w0 + w1 + w2);
    w0 *= winv; w1 *= winv; w2 *= winv;

    const float4* f0 = (const float4*)(feats + i0 * 64);
    const float4* f1 = (const float4*)(feats + i1 * 64);
    const float4* f2 = (const float4*)(feats + i2 * 64);

    float interp[64];
    #pragma unroll
    for (int q = 0; q < 16; ++q) {
        float4 a = f0[q], b = f1[q], c = f2[q];
        interp[4*q+0] = fmaf(w0, a.x, fmaf(w1, b.x, w2*c.x));
        interp[4*q+1] = fmaf(w0, a.y, fmaf(w1, b.y, w2*c.y));
        interp[4*q+2] = fmaf(w0, a.z, fmaf(w1, b.z, w2*c.z));
        interp[4*q+3] = fmaf(w0, a.w, fmaf(w1, b.w, w2*c.w));
    }

    // h = interp @ W1[0:64,:] + b1   (pos part of x is zeros -> rows 64..66 unused)
    float* hrow = hout + (size_t)tid * 128;
    #pragma unroll 1
    for (int cc = 0; cc < 128; cc += 32) {
        float acc[32];
        #pragma unroll
        for (int j = 0; j < 32; ++j) acc[j] = b1[cc + j];
        #pragma unroll
        for (int d = 0; d < 64; ++d) {
            float xd = interp[d];
            const float* wrow = W1 + d * 128 + cc;
            #pragma unroll
            for (int j = 0; j < 32; ++j) acc[j] = fmaf(xd, wrow[j], acc[j]);
        }
        #pragma unroll
        for (int j = 0; j < 32; j += 4) {
            *(float4*)(hrow + cc + j) =
                make_float4(acc[j], acc[j+1], acc[j+2], acc[j+3]);
        }
    }
}

// ---------------- Kernel B: batchnorm statistics (sum, sumsq per channel) ----------------
__global__ __launch_bounds__(256) void fp_stats(
    const float* __restrict__ h,
    float* __restrict__ stats,   // [0:128) sum, [128:256) sumsq
    int N)
{
    int c = threadIdx.x & 127;
    int p = threadIdx.x >> 7;   // 0 or 1
    int rpb = (N + gridDim.x - 1) / gridDim.x;
    int r0 = blockIdx.x * rpb;
    int r1 = r0 + rpb; if (r1 > N) r1 = N;
    float s = 0.0f, sq = 0.0f;
    for (int r = r0 + p; r < r1; r += 2) {
        float v = h[(size_t)r * 128 + c];
        s += v;
        sq = fmaf(v, v, sq);
    }
    __shared__ float ls[128], lsq[128];
    if (p == 1) { ls[c] = s; lsq[c] = sq; }
    __syncthreads();
    if (p == 0) {
        s += ls[c]; sq += lsq[c];
        atomicAdd(&stats[c], s);
        atomicAdd(&stats[128 + c], sq);
    }
}

// ---------------- Kernel C: batchnorm + ReLU + Linear2 ----------------
// 64 rows per block staged (normalized) in LDS; each wave owns a 32-col chunk
// (readfirstlane -> wave-uniform -> W2/b2 via scalar loads).
#define CROWS 64
#define CSTRIDE 129   // 129 % 32 == 1 -> 2-way bank aliasing (free)

__global__ __launch_bounds__(256) void fp_bn_mlp2(
    const float* __restrict__ h,
    const float* __restrict__ stats,
    const float* __restrict__ gamma,
    const float* __restrict__ beta,
    const float* __restrict__ W2,
    const float* __restrict__ b2,
    float* __restrict__ out,
    int N)
{
    __shared__ float scaleS[128], shiftS[128];
    __shared__ float hl[CROWS * CSTRIDE];
    int t = threadIdx.x;
    if (t < 128) {
        float inv = 1.0f / (float)N;
        float mu  = stats[t] * inv;
        float var = fmaf(-mu, mu, stats[128 + t] * inv);
        var = fmaxf(var, 0.0f);
        float is = rsqrtf(var + 1e-5f);
        float sc = gamma[t] * is;
        scaleS[t] = sc;
        shiftS[t] = beta[t] - mu * sc;
    }
    __syncthreads();

    size_t r0 = (size_t)blockIdx.x * CROWS;
    for (int i = t; i < CROWS * 128; i += 256) {
        int r = i >> 7, c = i & 127;
        size_t row = r0 + r;
        float v = (row < (size_t)N) ? h[row * 128 + c] : 0.0f;
        v = fmaf(v, scaleS[c], shiftS[c]);
        hl[r * CSTRIDE + c] = fmaxf(v, 0.0f);
    }
    __syncthreads();

    int lane = t & 63;
    int c0 = __builtin_amdgcn_readfirstlane((t >> 6) << 5);  // wave-uniform col base

    float acc[32];
    #pragma unroll
    for (int j = 0; j < 32; ++j) acc[j] = b2[c0 + j];
    #pragma unroll 8
    for (int k = 0; k < 128; ++k) {
        float x = hl[lane * CSTRIDE + k];
        const float* w2r = W2 + k * 128 + c0;
        #pragma unroll
        for (int j = 0; j < 32; ++j) acc[j] = fmaf(x, w2r[j], acc[j]);
    }

    size_t row = r0 + lane;
    if (row < (size_t)N) {
        float* orow = out + row * 128 + c0;
        #pragma unroll
        for (int j = 0; j < 32; j += 4) {
            *(float4*)(orow + j) = make_float4(acc[j], acc[j+1], acc[j+2], acc[j+3]);
        }
    }
}

extern "C" void kernel_launch(void* const* d_in, const int* in_sizes, int n_in,
                              void* d_out, int out_size, void* d_ws, size_t ws_size,
                              hipStream_t stream)
{
    (void)n_in; (void)out_size; (void)ws_size;
    const float* verts = (const float*)d_in[0];
    const float* cents = (const float*)d_in[1];
    const float* feats = (const float*)d_in[2];
    const float* W1    = (const float*)d_in[3];
    const float* b1    = (const float*)d_in[4];
    const float* gamma = (const float*)d_in[5];
    const float* beta  = (const float*)d_in[6];
    const float* W2    = (const float*)d_in[7];
    const float* b2    = (const float*)d_in[8];
    float* out = (float*)d_out;

    int N = in_sizes[0] / 3;
    int M = in_sizes[1] / 3;

    float* stats = (float*)d_ws;                       // 256 floats
    float* h     = (float*)((char*)d_ws + 1024);       // [N,128] fp32

    hipMemsetAsync(stats, 0, 256 * sizeof(float), stream);

    int blocksA = (N + 127) / 128;
    hipLaunchKernelGGL(fp_knn_interp_mlp1, dim3(blocksA), dim3(128), 0, stream,
                       verts, cents, feats, W1, b1, h, N, M);

    hipLaunchKernelGGL(fp_stats, dim3(512), dim3(256), 0, stream, h, stats, N);

    int blocksC = (N + CROWS - 1) / CROWS;
    hipLaunchKernelGGL(fp_bn_mlp2, dim3(blocksC), dim3(256), 0, stream,
                       h, stats, gamma, beta, W2, b2, out, N);
}

// Round 3
// 274.946 us; speedup vs baseline: 1.3777x; 1.3777x over previous
//
#include <hip/hip_runtime.h>

// ---------------- Prep: pack centroids as (x, y, z, 0.5*|c|^2) ----------------
__global__ __launch_bounds__(256) void fp_prep(
    const float* __restrict__ cents, float4* __restrict__ pk, int M)
{
    int m = blockIdx.x * 256 + threadIdx.x;
    if (m < M) {
        float x = cents[3*m], y = cents[3*m+1], z = cents[3*m+2];
        pk[m] = make_float4(x, y, z, 0.5f * (x*x + y*y + z*z));
    }
}

// ---------------- Kernel A: KNN (top-3) + IDW interp + Linear1 -> h^T ----------------
// 4 threads per vertex (each scans M/4 centroids), exact (s, idx) top-3 insert,
// shfl-merge, then block-cooperative GEMM1 with wave-uniform W1 scalar loads.
// h stored transposed [128, N] for coalesced stores.
#define APAD 65

__device__ __forceinline__ void ins3(float e, int ei,
                                     float& c0, float& c1, float& c2,
                                     int& i0, int& i1, int& i2)
{
    bool l0 = e < c0, l1 = e < c1, l2 = e < c2;
    c2 = l1 ? c1 : (l2 ? e  : c2);
    i2 = l1 ? i1 : (l2 ? ei : i2);
    c1 = l0 ? c0 : (l1 ? e  : c1);
    i1 = l0 ? i0 : (l1 ? ei : i1);
    c0 = l0 ? e  : c0;
    i0 = l0 ? ei : i0;
}

__global__ __launch_bounds__(256) void fp_knn_interp_mlp1(
    const float* __restrict__ verts,
    const float4* __restrict__ pk,
    const float* __restrict__ feats,
    const float* __restrict__ W1,
    const float* __restrict__ b1,
    float* __restrict__ hT,
    int N, int M)
{
    __shared__ float4 pkS[2048];
    float* interpL = (float*)pkS;   // reused after KNN phase: [64][APAD]

    int t = threadIdx.x;
    for (int i = t; i < M; i += 256) pkS[i] = pk[i];
    __syncthreads();

    int vloc = t >> 2;           // local vertex 0..63
    int p    = t & 3;            // quarter of the scan
    int v0   = blockIdx.x * 64;
    int vtx  = v0 + vloc;
    int vs   = vtx < N ? vtx : N - 1;
    float vx = verts[3*vs], vy = verts[3*vs+1], vz = verts[3*vs+2];

    // scan m = 4*i + p ; s = 0.5|c|^2 - v.c  (monotone with d^2), exact fp32
    float c0 = 3.4e38f, c1 = 3.4e38f, c2 = 3.4e38f;
    int   i0 = 0, i1 = 0, i2 = 0;
    int quarter = M >> 2;
    #pragma unroll 8
    for (int i = 0; i < quarter; ++i) {
        int m = (i << 2) | p;
        float4 c = pkS[m];
        float s = fmaf(-vx, c.x, fmaf(-vy, c.y, fmaf(-vz, c.z, c.w)));
        ins3(s, m, c0, c1, c2, i0, i1, i2);
    }
    // merge the 4 partial top-3 lists (partners are adjacent lanes)
    #pragma unroll
    for (int d = 1; d <= 2; d <<= 1) {
        float e0 = __shfl_xor(c0, d); int ei0 = __shfl_xor(i0, d);
        float e1 = __shfl_xor(c1, d); int ei1 = __shfl_xor(i1, d);
        float e2 = __shfl_xor(c2, d); int ei2 = __shfl_xor(i2, d);
        ins3(e0, ei0, c0, c1, c2, i0, i1, i2);
        ins3(e1, ei1, c0, c1, c2, i0, i1, i2);
        ins3(e2, ei2, c0, c1, c2, i0, i1, i2);
    }

    // exact d^2 for the winners (weights stay accurate)
    float4 ca = pkS[i0], cb = pkS[i1], cc = pkS[i2];
    float dx, dy, dz;
    dx = vx-ca.x; dy = vy-ca.y; dz = vz-ca.z;
    float d0 = fmaf(dx,dx, fmaf(dy,dy, dz*dz));
    dx = vx-cb.x; dy = vy-cb.y; dz = vz-cb.z;
    float d1 = fmaf(dx,dx, fmaf(dy,dy, dz*dz));
    dx = vx-cc.x; dy = vy-cc.y; dz = vz-cc.z;
    float d2 = fmaf(dx,dx, fmaf(dy,dy, dz*dz));

    bool z0 = (d0 == 0.0f), z1 = (d1 == 0.0f), z2 = (d2 == 0.0f);
    float w0, w1, w2;
    if (z0 || z1 || z2) {
        w0 = z0 ? 1.0f : 0.0f;
        w1 = z1 ? 1.0f : 0.0f;
        w2 = z2 ? 1.0f : 0.0f;
    } else {
        w0 = 1.0f / d0; w1 = 1.0f / d1; w2 = 1.0f / d2;
    }
    float winv = 1.0f / (w0 + w1 + w2);
    w0 *= winv; w1 *= winv; w2 *= winv;

    __syncthreads();   // everyone done reading pkS

    // each p-thread computes its 16-feature slice of interp
    {
        const float4* f0 = (const float4*)(feats + (size_t)i0 * 64) + 4*p;
        const float4* f1 = (const float4*)(feats + (size_t)i1 * 64) + 4*p;
        const float4* f2 = (const float4*)(feats + (size_t)i2 * 64) + 4*p;
        float* dst = interpL + vloc * APAD + 16*p;
        #pragma unroll
        for (int q = 0; q < 4; ++q) {
            float4 a = f0[q], b = f1[q], c = f2[q];
            dst[4*q+0] = fmaf(w0, a.x, fmaf(w1, b.x, w2*c.x));
            dst[4*q+1] = fmaf(w0, a.y, fmaf(w1, b.y, w2*c.y));
            dst[4*q+2] = fmaf(w0, a.z, fmaf(w1, b.z, w2*c.z));
            dst[4*q+3] = fmaf(w0, a.w, fmaf(w1, b.w, w2*c.w));
        }
    }
    __syncthreads();

    // block-cooperative GEMM1: wave w -> cols [32w,32w+32), lane -> vertex
    int lane = t & 63;
    int col0 = __builtin_amdgcn_readfirstlane((t >> 6) << 5);
    float acc[32];
    #pragma unroll
    for (int j = 0; j < 32; ++j) acc[j] = b1[col0 + j];
    #pragma unroll 4
    for (int d = 0; d < 64; ++d) {
        float x = interpL[lane * APAD + d];
        const float* wr = W1 + d * 128 + col0;
        #pragma unroll
        for (int j = 0; j < 32; ++j) acc[j] = fmaf(x, wr[j], acc[j]);
    }
    int gv = v0 + lane;
    if (gv < N) {
        #pragma unroll
        for (int j = 0; j < 32; ++j)
            hT[(size_t)(col0 + j) * N + gv] = acc[j];   // coalesced across lanes
    }
}

// ---------------- Kernel B: BN statistics over h^T ----------------
// 4 blocks per channel; float4 row reads; 2 atomics per block.
__global__ __launch_bounds__(256) void fp_stats(
    const float* __restrict__ hT, float* __restrict__ stats, int N)
{
    int c = blockIdx.x >> 2, part = blockIdx.x & 3;
    const float* row = hT + (size_t)c * N;
    float s = 0.0f, sq = 0.0f;
    if ((N & 3) == 0) {
        const float4* row4 = (const float4*)row;
        int n4 = N >> 2;
        int len = (n4 + 3) >> 2;
        int i0 = part * len;
        int i1 = i0 + len; if (i1 > n4) i1 = n4;
        for (int i = i0 + threadIdx.x; i < i1; i += 256) {
            float4 v = row4[i];
            s += (v.x + v.y) + (v.z + v.w);
            sq = fmaf(v.x, v.x, fmaf(v.y, v.y, fmaf(v.z, v.z, fmaf(v.w, v.w, sq))));
        }
    } else {
        int len = (N + 3) >> 2;
        int i0 = part * len;
        int i1 = i0 + len; if (i1 > N) i1 = N;
        for (int i = i0 + threadIdx.x; i < i1; i += 256) {
            float v = row[i];
            s += v; sq = fmaf(v, v, sq);
        }
    }
    #pragma unroll
    for (int o = 32; o; o >>= 1) { s += __shfl_down(s, o); sq += __shfl_down(sq, o); }
    __shared__ float rs[4], rq[4];
    int w = threadIdx.x >> 6;
    if ((threadIdx.x & 63) == 0) { rs[w] = s; rq[w] = sq; }
    __syncthreads();
    if (threadIdx.x == 0) {
        atomicAdd(&stats[c],       (rs[0] + rs[1]) + (rs[2] + rs[3]));
        atomicAdd(&stats[128 + c], (rq[0] + rq[1]) + (rq[2] + rq[3]));
    }
}

// ---------------- Kernel C: BN + ReLU + Linear2 ----------------
#define CROWS 64
#define CSTRIDE 129

__global__ __launch_bounds__(256) void fp_bn_mlp2(
    const float* __restrict__ hT,
    const float* __restrict__ stats,
    const float* __restrict__ gamma,
    const float* __restrict__ beta,
    const float* __restrict__ W2,
    const float* __restrict__ b2,
    float* __restrict__ out,
    int N)
{
    __shared__ float scaleS[128], shiftS[128];
    __shared__ float hl[CROWS * CSTRIDE];
    int t = threadIdx.x;
    if (t < 128) {
        float inv = 1.0f / (float)N;
        float mu  = stats[t] * inv;
        float var = fmaf(-mu, mu, stats[128 + t] * inv);
        var = fmaxf(var, 0.0f);
        float is = rsqrtf(var + 1e-5f);
        float sc = gamma[t] * is;
        scaleS[t] = sc;
        shiftS[t] = beta[t] - mu * sc;
    }
    __syncthreads();

    size_t r0 = (size_t)blockIdx.x * CROWS;

    // stage + normalize: wave reads 64 consecutive rows of one channel
    for (int i = t; i < 128 * CROWS; i += 256) {
        int c = i >> 6, r = i & 63;
        size_t row = r0 + r;
        float v = (row < (size_t)N) ? hT[(size_t)c * N + row] : 0.0f;
        v = fmaf(v, scaleS[c], shiftS[c]);
        hl[r * CSTRIDE + c] = fmaxf(v, 0.0f);
    }
    __syncthreads();

    int lane = t & 63;
    int c0 = __builtin_amdgcn_readfirstlane((t >> 6) << 5);

    float acc[32];
    #pragma unroll
    for (int j = 0; j < 32; ++j) acc[j] = b2[c0 + j];
    #pragma unroll 8
    for (int k = 0; k < 128; ++k) {
        float x = hl[lane * CSTRIDE + k];
        const float* wr = W2 + k * 128 + c0;
        #pragma unroll
        for (int j = 0; j < 32; ++j) acc[j] = fmaf(x, wr[j], acc[j]);
    }
    __syncthreads();

    // transpose through LDS for coalesced stores
    #pragma unroll
    for (int j = 0; j < 32; ++j) hl[lane * CSTRIDE + c0 + j] = acc[j];
    __syncthreads();

    for (int i = t; i < CROWS * 128; i += 256) {
        int r = i >> 7, c = i & 127;
        size_t row = r0 + r;
        if (row < (size_t)N) out[row * 128 + c] = hl[r * CSTRIDE + c];
    }
}

extern "C" void kernel_launch(void* const* d_in, const int* in_sizes, int n_in,
                              void* d_out, int out_size, void* d_ws, size_t ws_size,
                              hipStream_t stream)
{
    (void)n_in; (void)out_size; (void)ws_size;
    const float* verts = (const float*)d_in[0];
    const float* cents = (const float*)d_in[1];
    const float* feats = (const float*)d_in[2];
    const float* W1    = (const float*)d_in[3];
    const float* b1    = (const float*)d_in[4];
    const float* gamma = (const float*)d_in[5];
    const float* beta  = (const float*)d_in[6];
    const float* W2    = (const float*)d_in[7];
    const float* b2    = (const float*)d_in[8];
    float* out = (float*)d_out;

    int N = in_sizes[0] / 3;
    int M = in_sizes[1] / 3;

    float*  stats = (float*)d_ws;                          // 256 floats
    float4* pk    = (float4*)((char*)d_ws + 1024);         // [M] float4
    float*  hT    = (float*)((char*)d_ws + 1024 + (size_t)M * 16); // [128,N]

    hipMemsetAsync(stats, 0, 256 * sizeof(float), stream);

    hipLaunchKernelGGL(fp_prep, dim3((M + 255) / 256), dim3(256), 0, stream,
                       cents, pk, M);

    int blocksA = (N + 63) / 64;
    hipLaunchKernelGGL(fp_knn_interp_mlp1, dim3(blocksA), dim3(256), 0, stream,
                       verts, pk, feats, W1, b1, hT, N, M);

    hipLaunchKernelGGL(fp_stats, dim3(512), dim3(256), 0, stream, hT, stats, N);

    int blocksC = (N + CROWS - 1) / CROWS;
    hipLaunchKernelGGL(fp_bn_mlp2, dim3(blocksC), dim3(256), 0, stream,
                       hT, stats, gamma, beta, W2, b2, out, N);
}